// Round 4
// baseline (325.817 us; speedup 1.0000x reference)
//
#include <hip/hip_runtime.h>

#define DIM 128
#define NN 72
#define BB 2
#define NROWS (BB*NN*NN)   // 10368
#define BN (BB*NN)         // 144
#define GRID 648           // = NROWS/16 = BB*18*18 (both decompositions align)

// Grid-wide barrier. Safe: GRID=648 blocks, 16KB LDS + launch_bounds(256,3)
// guarantee >=3 blocks/CU * 256 CUs = 768 >= 648 co-resident blocks.
__device__ __forceinline__ void grid_barrier(unsigned* cnt) {
    __syncthreads();
    if (threadIdx.x == 0) {
        __threadfence();                      // release: publish phase-1 writes
        atomicAdd(cnt, 1u);
        while (__hip_atomic_load(cnt, __ATOMIC_ACQUIRE,
                                 __HIP_MEMORY_SCOPE_AGENT) < (unsigned)GRID) {}
    }
    __syncthreads();
    __threadfence();                          // acquire for all waves
}

__global__ __launch_bounds__(256, 3) void k_fused(
        const float* __restrict__ path, const float* __restrict__ Whz,
        const float* __restrict__ bhz,  const float* __restrict__ node,
        const float* __restrict__ Wzz,  const float* __restrict__ bzz,
        float* __restrict__ z, float* __restrict__ P1, float* __restrict__ P3,
        unsigned* cnt, float* __restrict__ out) {
    __shared__ float rows[16 * DIM];   // 8 KB
    __shared__ float comb[16 * DIM];   // 8 KB
    const int t   = threadIdx.x;
    const int blk = blockIdx.x;

    // ---------------- phase 1: z = path @ W_hz + b_hz (16 rows/block) -------
    {
        const int r0 = blk * 16;
        {
            float4* rs = (float4*)rows;
            const float4* pg = (const float4*)(path + r0 * DIM);
            rs[t]       = pg[t];
            rs[t + 256] = pg[t + 256];
        }
        __syncthreads();
        const int e2 = t & 63;
        const int rg = t >> 6;
        float2 bz = *(const float2*)&bhz[2 * e2];
        float2 acc[4];
#pragma unroll
        for (int r = 0; r < 4; r++) acc[r] = bz;
        const float* Wp = Whz + 2 * e2;
        float2 w[4], wn[4];
#pragma unroll
        for (int dd = 0; dd < 4; dd++) w[dd] = *(const float2*)&Wp[dd * DIM];
        for (int d4 = 0; d4 < DIM / 4; d4++) {
            if (d4 < DIM / 4 - 1) {
#pragma unroll
                for (int dd = 0; dd < 4; dd++)
                    wn[dd] = *(const float2*)&Wp[(4 * d4 + 4 + dd) * DIM];
            }
            float4 pr[4];
#pragma unroll
            for (int r = 0; r < 4; r++)
                pr[r] = *(const float4*)&rows[(rg + 4 * r) * DIM + 4 * d4];
#pragma unroll
            for (int dd = 0; dd < 4; dd++)
#pragma unroll
                for (int r = 0; r < 4; r++) {
                    float pv = ((const float*)&pr[r])[dd];
                    acc[r].x = fmaf(pv, w[dd].x, acc[r].x);
                    acc[r].y = fmaf(pv, w[dd].y, acc[r].y);
                }
#pragma unroll
            for (int dd = 0; dd < 4; dd++) w[dd] = wn[dd];
        }
#pragma unroll
        for (int r = 0; r < 4; r++)
            *(float2*)&z[(r0 + rg + 4 * r) * DIM + 2 * e2] = acc[r];
    }

    // ---- phase 1b: blocks 0..17 also compute P1/P3 = node @ W1/W3 ----------
    if (blk < 18) {
        const int r0 = blk * 8;
        {
            float4* cs = (float4*)comb;
            const float4* ng = (const float4*)(node + r0 * DIM);
            cs[t] = ng[t];   // 8 rows * 128 floats
        }
        __syncthreads();
        const int e  = t & 127;
        const int rr = t >> 7;
        float a1[4] = {0.f, 0.f, 0.f, 0.f};
        float a3[4] = {0.f, 0.f, 0.f, 0.f};
        const float* W1 = Wzz + e;
        const float* W3 = Wzz + 2 * DIM * DIM + e;
        for (int d = 0; d < DIM; d++) {
            float w1 = W1[d * DIM];
            float w3 = W3[d * DIM];
#pragma unroll
            for (int s = 0; s < 4; s++) {
                float pv = comb[(rr + 2 * s) * DIM + d];
                a1[s] = fmaf(pv, w1, a1[s]);
                a3[s] = fmaf(pv, w3, a3[s]);
            }
        }
#pragma unroll
        for (int s = 0; s < 4; s++) {
            int m = r0 + rr + 2 * s;
            P1[m * DIM + e] = a1[s];
            P3[m * DIM + e] = a3[s];
        }
    }

    grid_barrier(cnt);

    // ---------------- phase 2: tropical conv for 4x4 (i,j) tile -------------
    const int b   = blk / 324;
    const int rem = blk - b * 324;
    const int it  = rem / 18;
    const int jt  = rem - it * 18;
    const int i0 = it * 4, j0 = jt * 4;
    const int d  = t & 127;
    const int ty = t >> 7;    // k parity
    const float* zb = z + b * NN * NN * DIM;
    {
        float acc[16];
#pragma unroll
        for (int q = 0; q < 16; q++) acc[q] = -3.402823466e38f;

        float zi[4], zj[4], zin[4], zjn[4];
        int k = ty;
#pragma unroll
        for (int a = 0; a < 4; a++) zi[a] = zb[((i0 + a) * NN + k) * DIM + d];
#pragma unroll
        for (int c = 0; c < 4; c++) zj[c] = zb[(k * NN + (j0 + c)) * DIM + d];

        for (int it2 = 0; it2 < NN / 2; it2++) {
            int kn = k + 2;
            if (it2 < NN / 2 - 1) {
#pragma unroll
                for (int a = 0; a < 4; a++) zin[a] = zb[((i0 + a) * NN + kn) * DIM + d];
#pragma unroll
                for (int c = 0; c < 4; c++) zjn[c] = zb[(kn * NN + (j0 + c)) * DIM + d];
            }
#pragma unroll
            for (int a = 0; a < 4; a++)
#pragma unroll
                for (int c = 0; c < 4; c++)
                    acc[a * 4 + c] = fmaxf(acc[a * 4 + c], zi[a] + zj[c]);
#pragma unroll
            for (int a = 0; a < 4; a++) { zi[a] = zin[a]; zj[a] = zjn[a]; }
            k = kn;
        }

        if (ty == 1) {
#pragma unroll
            for (int q = 0; q < 16; q++) comb[q * DIM + d] = acc[q];
        }
        __syncthreads();
        if (ty == 0) {
            // merge halves, add self-term, stage zmax rows in LDS (q = a*4+c)
#pragma unroll
            for (int a = 0; a < 4; a++)
#pragma unroll
                for (int c = 0; c < 4; c++) {
                    int q = a * 4 + c;
                    float m = fmaxf(acc[q], comb[q * DIM + d]);
                    int idx = ((i0 + a) * NN + (j0 + c)) * DIM + d;
                    rows[q * DIM + d] = fmaxf(m, zb[idx]);
                }
        }
    }
    __syncthreads();

    // ---------------- phase 3: out = relu(zmax@W2 + P1 + P3 + b) ------------
    {
        const int e2 = t & 63;
        const int rg = t >> 6;
        float2 acc[4];
#pragma unroll
        for (int r = 0; r < 4; r++) acc[r] = make_float2(0.f, 0.f);

        const float* Wp = Wzz + DIM * DIM + 2 * e2;   // W2 block
        float2 w[4], wn[4];
#pragma unroll
        for (int dd = 0; dd < 4; dd++) w[dd] = *(const float2*)&Wp[dd * DIM];
        for (int d4 = 0; d4 < DIM / 4; d4++) {
            if (d4 < DIM / 4 - 1) {
#pragma unroll
                for (int dd = 0; dd < 4; dd++)
                    wn[dd] = *(const float2*)&Wp[(4 * d4 + 4 + dd) * DIM];
            }
            float4 pr[4];
#pragma unroll
            for (int r = 0; r < 4; r++)
                pr[r] = *(const float4*)&rows[(rg + 4 * r) * DIM + 4 * d4];
#pragma unroll
            for (int dd = 0; dd < 4; dd++)
#pragma unroll
                for (int r = 0; r < 4; r++) {
                    float pv = ((const float*)&pr[r])[dd];
                    acc[r].x = fmaf(pv, w[dd].x, acc[r].x);
                    acc[r].y = fmaf(pv, w[dd].y, acc[r].y);
                }
#pragma unroll
            for (int dd = 0; dd < 4; dd++) w[dd] = wn[dd];
        }

        float2 bz = *(const float2*)&bzz[2 * e2];
#pragma unroll
        for (int r = 0; r < 4; r++) {
            int q = rg + 4 * r;        // LDS row index = a*4+c
            int a = q >> 2, c = q & 3;
            int orow = b * NN * NN + (i0 + a) * NN + (j0 + c);
            float2 v1 = *(const float2*)&P1[(b * NN + i0 + a) * DIM + 2 * e2];
            float2 v3 = *(const float2*)&P3[(b * NN + j0 + c) * DIM + 2 * e2];
            float ox = fmaxf(acc[r].x + v1.x + v3.x + bz.x, 0.f);
            float oy = fmaxf(acc[r].y + v1.y + v3.y + bz.y, 0.f);
            *(float2*)&out[orow * DIM + 2 * e2] = make_float2(ox, oy);
        }
    }
}

extern "C" void kernel_launch(void* const* d_in, const int* in_sizes, int n_in,
                              void* d_out, int out_size, void* d_ws, size_t ws_size,
                              hipStream_t stream) {
    const float* node = (const float*)d_in[0];
    const float* path = (const float*)d_in[1];
    const float* Whz  = (const float*)d_in[2];
    const float* bhz  = (const float*)d_in[3];
    const float* Wzz  = (const float*)d_in[4];
    const float* bzz  = (const float*)d_in[5];
    float* out = (float*)d_out;

    unsigned* cnt = (unsigned*)d_ws;        // barrier counter (zeroed below)
    float* base = (float*)d_ws;
    float* z  = base + 256;                 // 1 KB offset, keeps z aligned
    float* P1 = z + NROWS * DIM;
    float* P3 = P1 + BN * DIM;

    hipMemsetAsync(d_ws, 0, 64, stream);    // zero barrier counter (graph node)
    hipLaunchKernelGGL(k_fused, dim3(GRID), dim3(256), 0, stream,
                       path, Whz, bhz, node, Wzz, bzz, z, P1, P3, cnt, out);
}

// Round 5
// 109.649 us; speedup vs baseline: 2.9715x; 2.9715x over previous
//
#include <hip/hip_runtime.h>

#define DIM 128
#define NN 72
#define BB 2
#define NROWS (BB*NN*NN)   // 10368
#define BN (BB*NN)         // 144
#define ZBLOCKS (NROWS/16) // 648

// ---------------------------------------------------------------------------
// Kernel 1 (unchanged from R3, verified): z = path@W_hz + b_hz (16 rows/blk),
// blocks 648..665 also compute P1/P3 = node@W1/W3.
// ---------------------------------------------------------------------------
__global__ __launch_bounds__(256) void k_phase1(const float* __restrict__ path,
                                                const float* __restrict__ Whz,
                                                const float* __restrict__ bhz,
                                                float* __restrict__ z,
                                                const float* __restrict__ node,
                                                const float* __restrict__ Wzz,
                                                float* __restrict__ P1,
                                                float* __restrict__ P3) {
    __shared__ float rows[16 * DIM];   // 8 KB
    const int t = threadIdx.x;

    if (blockIdx.x < ZBLOCKS) {
        const int r0 = blockIdx.x * 16;
        {
            float4* rs = (float4*)rows;
            const float4* pg = (const float4*)(path + r0 * DIM);
            rs[t]       = pg[t];
            rs[t + 256] = pg[t + 256];
        }
        __syncthreads();

        const int e2 = t & 63;
        const int rg = t >> 6;
        float2 bz = *(const float2*)&bhz[2 * e2];
        float2 acc[4];
#pragma unroll
        for (int r = 0; r < 4; r++) acc[r] = bz;

        const float* Wp = Whz + 2 * e2;
        float2 w[4], wn[4];
#pragma unroll
        for (int dd = 0; dd < 4; dd++) w[dd] = *(const float2*)&Wp[dd * DIM];

        for (int d4 = 0; d4 < DIM / 4; d4++) {
            if (d4 < DIM / 4 - 1) {
#pragma unroll
                for (int dd = 0; dd < 4; dd++)
                    wn[dd] = *(const float2*)&Wp[(4 * d4 + 4 + dd) * DIM];
            }
            float4 pr[4];
#pragma unroll
            for (int r = 0; r < 4; r++)
                pr[r] = *(const float4*)&rows[(rg + 4 * r) * DIM + 4 * d4];
#pragma unroll
            for (int dd = 0; dd < 4; dd++)
#pragma unroll
                for (int r = 0; r < 4; r++) {
                    float pv = ((const float*)&pr[r])[dd];
                    acc[r].x = fmaf(pv, w[dd].x, acc[r].x);
                    acc[r].y = fmaf(pv, w[dd].y, acc[r].y);
                }
#pragma unroll
            for (int dd = 0; dd < 4; dd++) w[dd] = wn[dd];
        }
#pragma unroll
        for (int r = 0; r < 4; r++)
            *(float2*)&z[(r0 + rg + 4 * r) * DIM + 2 * e2] = acc[r];
    } else {
        const int r0 = (blockIdx.x - ZBLOCKS) * 8;
        {
            float4* rs = (float4*)rows;
            const float4* ng = (const float4*)(node + r0 * DIM);
            rs[t] = ng[t];
        }
        __syncthreads();
        const int e  = t & 127;
        const int rr = t >> 7;
        float a1[4] = {0.f, 0.f, 0.f, 0.f};
        float a3[4] = {0.f, 0.f, 0.f, 0.f};
        const float* W1 = Wzz + e;
        const float* W3 = Wzz + 2 * DIM * DIM + e;
        for (int d = 0; d < DIM; d++) {
            float w1 = W1[d * DIM];
            float w3 = W3[d * DIM];
#pragma unroll
            for (int s = 0; s < 4; s++) {
                float pv = rows[(rr + 2 * s) * DIM + d];
                a1[s] = fmaf(pv, w1, a1[s]);
                a3[s] = fmaf(pv, w3, a3[s]);
            }
        }
#pragma unroll
        for (int s = 0; s < 4; s++) {
            int m = r0 + rr + 2 * s;
            P1[m * DIM + e] = a1[s];
            P3[m * DIM + e] = a3[s];
        }
    }
}

// ---------------------------------------------------------------------------
// Kernel 2: fused tropical conv + output GEMM (R4 phases 2+3, no barrier).
// 4x4 (i,j) tile per block; zmax rows handed phase2->phase3 through LDS —
// the 5.3 MB zmax global round-trip is gone, as is one dispatch.
// ---------------------------------------------------------------------------
__global__ __launch_bounds__(256, 4) void k_trop_out(
        const float* __restrict__ z,   const float* __restrict__ Wzz,
        const float* __restrict__ bzz, const float* __restrict__ P1,
        const float* __restrict__ P3,  float* __restrict__ out) {
    __shared__ float rows[16 * DIM];   // zmax tile (8 KB)
    __shared__ float comb[16 * DIM];   // k-split merge (8 KB)
    const int t   = threadIdx.x;
    const int blk = blockIdx.x;
    const int b   = blk / 324;
    const int rem = blk - b * 324;
    const int it  = rem / 18;
    const int jt  = rem - it * 18;
    const int i0 = it * 4, j0 = jt * 4;
    const int d  = t & 127;
    const int ty = t >> 7;    // k parity
    const float* zb = z + b * NN * NN * DIM;

    // ---- phase 2: tropical max-plus over k, 2-way k-split + prefetch ------
    {
        float acc[16];
#pragma unroll
        for (int q = 0; q < 16; q++) acc[q] = -3.402823466e38f;

        float zi[4], zj[4], zin[4], zjn[4];
        int k = ty;
#pragma unroll
        for (int a = 0; a < 4; a++) zi[a] = zb[((i0 + a) * NN + k) * DIM + d];
#pragma unroll
        for (int c = 0; c < 4; c++) zj[c] = zb[(k * NN + (j0 + c)) * DIM + d];

        for (int it2 = 0; it2 < NN / 2; it2++) {
            int kn = k + 2;
            if (it2 < NN / 2 - 1) {
#pragma unroll
                for (int a = 0; a < 4; a++) zin[a] = zb[((i0 + a) * NN + kn) * DIM + d];
#pragma unroll
                for (int c = 0; c < 4; c++) zjn[c] = zb[(kn * NN + (j0 + c)) * DIM + d];
            }
#pragma unroll
            for (int a = 0; a < 4; a++)
#pragma unroll
                for (int c = 0; c < 4; c++)
                    acc[a * 4 + c] = fmaxf(acc[a * 4 + c], zi[a] + zj[c]);
#pragma unroll
            for (int a = 0; a < 4; a++) { zi[a] = zin[a]; zj[a] = zjn[a]; }
            k = kn;
        }

        if (ty == 1) {
#pragma unroll
            for (int q = 0; q < 16; q++) comb[q * DIM + d] = acc[q];
        }
        __syncthreads();
        if (ty == 0) {
#pragma unroll
            for (int a = 0; a < 4; a++)
#pragma unroll
                for (int c = 0; c < 4; c++) {
                    int q = a * 4 + c;
                    float m = fmaxf(acc[q], comb[q * DIM + d]);
                    int idx = ((i0 + a) * NN + (j0 + c)) * DIM + d;
                    rows[q * DIM + d] = fmaxf(m, zb[idx]);
                }
        }
    }
    __syncthreads();

    // ---- phase 3: out = relu(zmax@W2 + P1[b,i] + P3[b,j] + b_zz) ----------
    {
        const int e2 = t & 63;
        const int rg = t >> 6;
        float2 acc[4];
#pragma unroll
        for (int r = 0; r < 4; r++) acc[r] = make_float2(0.f, 0.f);

        const float* Wp = Wzz + DIM * DIM + 2 * e2;   // W2 block
        float2 w[4], wn[4];
#pragma unroll
        for (int dd = 0; dd < 4; dd++) w[dd] = *(const float2*)&Wp[dd * DIM];
        for (int d4 = 0; d4 < DIM / 4; d4++) {
            if (d4 < DIM / 4 - 1) {
#pragma unroll
                for (int dd = 0; dd < 4; dd++)
                    wn[dd] = *(const float2*)&Wp[(4 * d4 + 4 + dd) * DIM];
            }
            float4 pr[4];
#pragma unroll
            for (int r = 0; r < 4; r++)
                pr[r] = *(const float4*)&rows[(rg + 4 * r) * DIM + 4 * d4];
#pragma unroll
            for (int dd = 0; dd < 4; dd++)
#pragma unroll
                for (int r = 0; r < 4; r++) {
                    float pv = ((const float*)&pr[r])[dd];
                    acc[r].x = fmaf(pv, w[dd].x, acc[r].x);
                    acc[r].y = fmaf(pv, w[dd].y, acc[r].y);
                }
#pragma unroll
            for (int dd = 0; dd < 4; dd++) w[dd] = wn[dd];
        }

        float2 bz = *(const float2*)&bzz[2 * e2];
#pragma unroll
        for (int r = 0; r < 4; r++) {
            int q = rg + 4 * r;        // LDS row index = a*4+c
            int a = q >> 2, c = q & 3;
            int orow = b * NN * NN + (i0 + a) * NN + (j0 + c);
            float2 v1 = *(const float2*)&P1[(b * NN + i0 + a) * DIM + 2 * e2];
            float2 v3 = *(const float2*)&P3[(b * NN + j0 + c) * DIM + 2 * e2];
            float ox = fmaxf(acc[r].x + v1.x + v3.x + bz.x, 0.f);
            float oy = fmaxf(acc[r].y + v1.y + v3.y + bz.y, 0.f);
            *(float2*)&out[orow * DIM + 2 * e2] = make_float2(ox, oy);
        }
    }
}

extern "C" void kernel_launch(void* const* d_in, const int* in_sizes, int n_in,
                              void* d_out, int out_size, void* d_ws, size_t ws_size,
                              hipStream_t stream) {
    const float* node = (const float*)d_in[0];
    const float* path = (const float*)d_in[1];
    const float* Whz  = (const float*)d_in[2];
    const float* bhz  = (const float*)d_in[3];
    const float* Wzz  = (const float*)d_in[4];
    const float* bzz  = (const float*)d_in[5];
    float* out = (float*)d_out;

    float* z  = (float*)d_ws;
    float* P1 = z + NROWS * DIM;
    float* P3 = P1 + BN * DIM;

    hipLaunchKernelGGL(k_phase1,   dim3(ZBLOCKS + 18), dim3(256), 0, stream,
                       path, Whz, bhz, z, node, Wzz, P1, P3);
    hipLaunchKernelGGL(k_trop_out, dim3(BB * 18 * 18), dim3(256), 0, stream,
                       z, Wzz, bzz, P1, P3, out);
}

// Round 6
// 107.166 us; speedup vs baseline: 3.0403x; 1.0232x over previous
//
#include <hip/hip_runtime.h>

#define DIM 128
#define NN 72
#define BB 2
#define NSQ (NN*NN)        // 5184
#define NROWS (BB*NSQ)     // 10368
#define BN (BB*NN)         // 144
#define ZBLOCKS (NROWS/16) // 648

// ---------------------------------------------------------------------------
// Kernel 1: z = path@W_hz + b_hz (16 rows/blk), ALSO writes zT (transposed
// (i,j) layout) so k_trop_out's zj reads are k-sequential. Blocks 648..665
// compute P1/P3 = node@W1/W3. W-stream prefetch depth 2 (8 K per iter).
// ---------------------------------------------------------------------------
__global__ __launch_bounds__(256, 4) void k_phase1(const float* __restrict__ path,
                                                   const float* __restrict__ Whz,
                                                   const float* __restrict__ bhz,
                                                   float* __restrict__ z,
                                                   float* __restrict__ zT,
                                                   const float* __restrict__ node,
                                                   const float* __restrict__ Wzz,
                                                   float* __restrict__ P1,
                                                   float* __restrict__ P3) {
    __shared__ float rows[16 * DIM];   // 8 KB
    const int t = threadIdx.x;

    if (blockIdx.x < ZBLOCKS) {
        const int r0 = blockIdx.x * 16;
        {
            float4* rs = (float4*)rows;
            const float4* pg = (const float4*)(path + r0 * DIM);
            rs[t]       = pg[t];
            rs[t + 256] = pg[t + 256];
        }
        __syncthreads();

        const int e2 = t & 63;
        const int rg = t >> 6;
        float2 bz = *(const float2*)&bhz[2 * e2];
        float2 acc[4];
#pragma unroll
        for (int r = 0; r < 4; r++) acc[r] = bz;

        const float* Wp = Whz + 2 * e2;
        float2 w0[4], w1[4], n0[4], n1[4];
#pragma unroll
        for (int dd = 0; dd < 4; dd++) {
            w0[dd] = *(const float2*)&Wp[dd * DIM];
            w1[dd] = *(const float2*)&Wp[(4 + dd) * DIM];
        }
        for (int d8 = 0; d8 < 16; d8++) {
            if (d8 < 15) {
#pragma unroll
                for (int dd = 0; dd < 4; dd++) {
                    n0[dd] = *(const float2*)&Wp[(8 * d8 + 8 + dd) * DIM];
                    n1[dd] = *(const float2*)&Wp[(8 * d8 + 12 + dd) * DIM];
                }
            }
            float4 pa[4], pb[4];
#pragma unroll
            for (int r = 0; r < 4; r++) {
                pa[r] = *(const float4*)&rows[(rg + 4 * r) * DIM + 8 * d8];
                pb[r] = *(const float4*)&rows[(rg + 4 * r) * DIM + 8 * d8 + 4];
            }
#pragma unroll
            for (int dd = 0; dd < 4; dd++)
#pragma unroll
                for (int r = 0; r < 4; r++) {
                    float pv = ((const float*)&pa[r])[dd];
                    acc[r].x = fmaf(pv, w0[dd].x, acc[r].x);
                    acc[r].y = fmaf(pv, w0[dd].y, acc[r].y);
                }
#pragma unroll
            for (int dd = 0; dd < 4; dd++)
#pragma unroll
                for (int r = 0; r < 4; r++) {
                    float pv = ((const float*)&pb[r])[dd];
                    acc[r].x = fmaf(pv, w1[dd].x, acc[r].x);
                    acc[r].y = fmaf(pv, w1[dd].y, acc[r].y);
                }
#pragma unroll
            for (int dd = 0; dd < 4; dd++) { w0[dd] = n0[dd]; w1[dd] = n1[dd]; }
        }
#pragma unroll
        for (int r = 0; r < 4; r++) {
            int row = r0 + rg + 4 * r;
            *(float2*)&z[row * DIM + 2 * e2] = acc[r];
            int b  = row / NSQ;
            int ij = row - b * NSQ;
            int i  = ij / NN;
            int j  = ij - i * NN;
            *(float2*)&zT[(b * NSQ + j * NN + i) * DIM + 2 * e2] = acc[r];
        }
    } else {
        const int r0 = (blockIdx.x - ZBLOCKS) * 8;
        {
            float4* rs = (float4*)rows;
            const float4* ng = (const float4*)(node + r0 * DIM);
            rs[t] = ng[t];
        }
        __syncthreads();
        const int e  = t & 127;
        const int rr = t >> 7;
        float a1[4] = {0.f, 0.f, 0.f, 0.f};
        float a3[4] = {0.f, 0.f, 0.f, 0.f};
        const float* W1 = Wzz + e;
        const float* W3 = Wzz + 2 * DIM * DIM + e;
        for (int d = 0; d < DIM; d++) {
            float w1 = W1[d * DIM];
            float w3 = W3[d * DIM];
#pragma unroll
            for (int s = 0; s < 4; s++) {
                float pv = rows[(rr + 2 * s) * DIM + d];
                a1[s] = fmaf(pv, w1, a1[s]);
                a3[s] = fmaf(pv, w3, a3[s]);
            }
        }
#pragma unroll
        for (int s = 0; s < 4; s++) {
            int m = r0 + rr + 2 * s;
            P1[m * DIM + e] = a1[s];
            P3[m * DIM + e] = a3[s];
        }
    }
}

// ---------------------------------------------------------------------------
// Kernel 2: fused tropical conv + output GEMM. Phase 2 reads 8 k-sequential
// streams (zi from z, zj from zT), 4 k's per group per ty => 32 loads in
// flight. Phase 3 GEMM sources zmax tile from LDS; W2 prefetch depth 2.
// ---------------------------------------------------------------------------
__global__ __launch_bounds__(256, 3) void k_trop_out(
        const float* __restrict__ z,   const float* __restrict__ zT,
        const float* __restrict__ Wzz, const float* __restrict__ bzz,
        const float* __restrict__ P1,  const float* __restrict__ P3,
        float* __restrict__ out) {
    __shared__ float rows[16 * DIM];   // zmax tile (8 KB)
    __shared__ float comb[16 * DIM];   // k-split merge (8 KB)
    const int t   = threadIdx.x;
    const int blk = blockIdx.x;
    const int b   = blk / 324;
    const int rem = blk - b * 324;
    const int it  = rem / 18;
    const int jt  = rem - it * 18;
    const int i0 = it * 4, j0 = jt * 4;
    const int d  = t & 127;
    const int ty = t >> 7;    // k parity
    const float* zb  = z  + b * NSQ * DIM;
    const float* zTb = zT + b * NSQ * DIM;

    // ---- phase 2: max-plus over k; 2-way k-split, groups of 4 k's ---------
    {
        float acc[16];
#pragma unroll
        for (int q = 0; q < 16; q++) acc[q] = -3.402823466e38f;

        float cur[32], nxt[32];   // [kk*8 + s]: s=0..3 zi, 4..7 zj
#pragma unroll
        for (int kk = 0; kk < 4; kk++) {
            int k = ty + 2 * kk;
#pragma unroll
            for (int s = 0; s < 4; s++) {
                cur[kk * 8 + s]     = zb [((i0 + s) * NN + k) * DIM + d];
                cur[kk * 8 + 4 + s] = zTb[((j0 + s) * NN + k) * DIM + d];
            }
        }
        for (int g = 0; g < 9; g++) {
            if (g < 8) {
#pragma unroll
                for (int kk = 0; kk < 4; kk++) {
                    int k = ty + 2 * kk + 8 * (g + 1);
#pragma unroll
                    for (int s = 0; s < 4; s++) {
                        nxt[kk * 8 + s]     = zb [((i0 + s) * NN + k) * DIM + d];
                        nxt[kk * 8 + 4 + s] = zTb[((j0 + s) * NN + k) * DIM + d];
                    }
                }
            }
#pragma unroll
            for (int kk = 0; kk < 4; kk++)
#pragma unroll
                for (int a = 0; a < 4; a++)
#pragma unroll
                    for (int c = 0; c < 4; c++)
                        acc[a * 4 + c] = fmaxf(acc[a * 4 + c],
                                               cur[kk * 8 + a] + cur[kk * 8 + 4 + c]);
#pragma unroll
            for (int q = 0; q < 32; q++) cur[q] = nxt[q];
        }

        if (ty == 1) {
#pragma unroll
            for (int q = 0; q < 16; q++) comb[q * DIM + d] = acc[q];
        }
        __syncthreads();
        if (ty == 0) {
#pragma unroll
            for (int a = 0; a < 4; a++)
#pragma unroll
                for (int c = 0; c < 4; c++) {
                    int q = a * 4 + c;
                    float m = fmaxf(acc[q], comb[q * DIM + d]);
                    int idx = ((i0 + a) * NN + (j0 + c)) * DIM + d;
                    rows[q * DIM + d] = fmaxf(m, zb[idx]);
                }
        }
    }
    __syncthreads();

    // ---- phase 3: out = relu(zmax@W2 + P1[b,i] + P3[b,j] + b_zz) ----------
    {
        const int e2 = t & 63;
        const int rg = t >> 6;
        float2 acc[4];
#pragma unroll
        for (int r = 0; r < 4; r++) acc[r] = make_float2(0.f, 0.f);

        const float* Wp = Wzz + DIM * DIM + 2 * e2;   // W2 block
        float2 w0[4], w1[4], n0[4], n1[4];
#pragma unroll
        for (int dd = 0; dd < 4; dd++) {
            w0[dd] = *(const float2*)&Wp[dd * DIM];
            w1[dd] = *(const float2*)&Wp[(4 + dd) * DIM];
        }
        for (int d8 = 0; d8 < 16; d8++) {
            if (d8 < 15) {
#pragma unroll
                for (int dd = 0; dd < 4; dd++) {
                    n0[dd] = *(const float2*)&Wp[(8 * d8 + 8 + dd) * DIM];
                    n1[dd] = *(const float2*)&Wp[(8 * d8 + 12 + dd) * DIM];
                }
            }
            float4 pa[4], pb[4];
#pragma unroll
            for (int r = 0; r < 4; r++) {
                pa[r] = *(const float4*)&rows[(rg + 4 * r) * DIM + 8 * d8];
                pb[r] = *(const float4*)&rows[(rg + 4 * r) * DIM + 8 * d8 + 4];
            }
#pragma unroll
            for (int dd = 0; dd < 4; dd++)
#pragma unroll
                for (int r = 0; r < 4; r++) {
                    float pv = ((const float*)&pa[r])[dd];
                    acc[r].x = fmaf(pv, w0[dd].x, acc[r].x);
                    acc[r].y = fmaf(pv, w0[dd].y, acc[r].y);
                }
#pragma unroll
            for (int dd = 0; dd < 4; dd++)
#pragma unroll
                for (int r = 0; r < 4; r++) {
                    float pv = ((const float*)&pb[r])[dd];
                    acc[r].x = fmaf(pv, w1[dd].x, acc[r].x);
                    acc[r].y = fmaf(pv, w1[dd].y, acc[r].y);
                }
#pragma unroll
            for (int dd = 0; dd < 4; dd++) { w0[dd] = n0[dd]; w1[dd] = n1[dd]; }
        }

        float2 bz = *(const float2*)&bzz[2 * e2];
#pragma unroll
        for (int r = 0; r < 4; r++) {
            int q = rg + 4 * r;        // LDS row index = a*4+c
            int a = q >> 2, c = q & 3;
            int orow = b * NSQ + (i0 + a) * NN + (j0 + c);
            float2 v1 = *(const float2*)&P1[(b * NN + i0 + a) * DIM + 2 * e2];
            float2 v3 = *(const float2*)&P3[(b * NN + j0 + c) * DIM + 2 * e2];
            float ox = fmaxf(acc[r].x + v1.x + v3.x + bz.x, 0.f);
            float oy = fmaxf(acc[r].y + v1.y + v3.y + bz.y, 0.f);
            *(float2*)&out[orow * DIM + 2 * e2] = make_float2(ox, oy);
        }
    }
}

extern "C" void kernel_launch(void* const* d_in, const int* in_sizes, int n_in,
                              void* d_out, int out_size, void* d_ws, size_t ws_size,
                              hipStream_t stream) {
    const float* node = (const float*)d_in[0];
    const float* path = (const float*)d_in[1];
    const float* Whz  = (const float*)d_in[2];
    const float* bhz  = (const float*)d_in[3];
    const float* Wzz  = (const float*)d_in[4];
    const float* bzz  = (const float*)d_in[5];
    float* out = (float*)d_out;

    float* z  = (float*)d_ws;
    float* zT = z  + NROWS * DIM;
    float* P1 = zT + NROWS * DIM;
    float* P3 = P1 + BN * DIM;

    hipLaunchKernelGGL(k_phase1,   dim3(ZBLOCKS + 18), dim3(256), 0, stream,
                       path, Whz, bhz, z, zT, node, Wzz, P1, P3);
    hipLaunchKernelGGL(k_trop_out, dim3(BB * 18 * 18), dim3(256), 0, stream,
                       z, zT, Wzz, bzz, P1, P3, out);
}